// Round 21
// baseline (281.687 us; speedup 1.0000x reference)
//
#include <hip/hip_runtime.h>
#include <hip/hip_bf16.h>

#define B_ 8
#define C_ 192
#define G_ 256
#define E_ 384
#define R_ 4
#define T_ 8192
#define L_ 3
#define K_ 3

typedef __attribute__((ext_vector_type(4))) float f32x4;
typedef __attribute__((ext_vector_type(16))) float f32x16;
typedef __attribute__((ext_vector_type(8))) short bf16x8;
typedef __attribute__((ext_vector_type(4))) short bf16x4;

// LDS row strides chosen so (stride in dwords) mod 32 = 5 -> 32-lane
// row-strided ds_read_b128 is bank-conflict-free (5 coprime 32).
#define HS_STRIDE  (C_ + 10)   // 202 el = 404 B = 101 dw
#define H1S_STRIDE (E_ + 10)   // 394 el = 788 B = 197 dw

static __device__ __forceinline__ float bf2f(short u) {
    union { float f; unsigned int i; } z;
    z.i = ((unsigned int)(unsigned short)u) << 16;
    return z.f;
}

// tanh-form GELU: max abs err vs erf-form ~1e-3 (absmax 0.078 measured).
static __device__ __forceinline__ float gelu_fast(float x) {
    float x2 = x * x;
    float inner = fmaf(0.044715f * x, x2, x);
    float e = __expf(1.5957691216057308f * inner);   // e^{2z}
    float r = 1.0f / (e + 1.0f);
    float t = fmaf(-2.0f, r, 1.0f);                  // tanh(z)
    float s = 0.5f * x;
    return fmaf(s, t, s);
}

// ---------- all 4 adapter projections in one launch --------------------
__global__ __launch_bounds__(256) void adapters_kernel(
    const float* __restrict__ g2,
    const float* __restrict__ w0, const float* __restrict__ bi0, float* __restrict__ o0,
    const float* __restrict__ w1, const float* __restrict__ bi1, float* __restrict__ o1,
    const float* __restrict__ w2, const float* __restrict__ bi2, float* __restrict__ o2,
    const float* __restrict__ w3, const float* __restrict__ bi3, float* __restrict__ o3)
{
    const int N0 = L_ * B_ * (C_ * R_);     // 18432
    const int N1 = L_ * B_ * (E_ * R_);     // 36864
    int idx = blockIdx.x * 256 + threadIdx.x;
    const float* w; const float* bi; float* o; int rows; int li;
    if (idx < N0)                      { w=w0; bi=bi0; o=o0; rows=C_*R_; li=idx; }
    else if ((idx -= N0) < N1)         { w=w1; bi=bi1; o=o1; rows=E_*R_; li=idx; }
    else if ((idx -= N1) < N1)         { w=w2; bi=bi2; o=o2; rows=E_*R_; li=idx; }
    else if ((idx -= N1) < N0)         { w=w3; bi=bi3; o=o3; rows=C_*R_; li=idx; }
    else return;
    int bb = li & 7;
    int lr = li >> 3;
    const float4* wr = (const float4*)(w + (size_t)lr * G_);
    const float4* gb = (const float4*)(g2 + (size_t)bb * G_);
    float s = bi[lr];
#pragma unroll 8
    for (int g = 0; g < G_ / 4; ++g) {
        float4 a = gb[g], b = wr[g];
        s = fmaf(a.x, b.x, s); s = fmaf(a.y, b.y, s);
        s = fmaf(a.z, b.z, s); s = fmaf(a.w, b.w, s);
    }
    o[((size_t)(lr / rows) * B_ + bb) * rows + (lr % rows)] = s;
}

// ---------- W1eff, W2eff (plain; LN affine applied in staging) ---------
__global__ __launch_bounds__(256) void builds_kernel(
    const float* __restrict__ p1w, const float* __restrict__ p2w,
    const float* __restrict__ A1in, const float* __restrict__ A1out,
    const float* __restrict__ A2in, const float* __restrict__ A2out,
    __hip_bfloat16* __restrict__ W1, __hip_bfloat16* __restrict__ W2)
{
    const int W1B = (L_ * B_ * E_ * C_) / 256;   // 6912 blocks
    int blk = blockIdx.x;
    if (blk < W1B) {
        int idx = blk * 256 + threadIdx.x;
        int c = idx % C_;
        int e = (idx / C_) % E_;
        int b = (idx / (C_ * E_)) % B_;
        int l = idx / (C_ * E_ * B_);
        float v = p1w[((size_t)l * E_ + e) * C_ + c];
        const float* ai = A1in + ((size_t)l * B_ + b) * (C_ * R_);
        const float* ao = A1out + ((size_t)l * B_ + b) * (R_ * E_);
#pragma unroll
        for (int r = 0; r < R_; ++r) v = fmaf(ai[c * R_ + r], ao[r * E_ + e], v);
        W1[idx] = __float2bfloat16(v);
    } else {
        int idx = (blk - W1B) * 256 + threadIdx.x;
        int e = idx % E_;
        int c = (idx / E_) % C_;
        int b = (idx / (C_ * E_)) % B_;
        int l = idx / (C_ * E_ * B_);
        float v = p2w[((size_t)l * C_ + c) * E_ + e];
        const float* ai = A2in + ((size_t)l * B_ + b) * (E_ * R_);
        const float* ao = A2out + ((size_t)l * B_ + b) * (R_ * C_);
#pragma unroll
        for (int r = 0; r < R_; ++r) v = fmaf(ai[e * R_ + r], ao[r * C_ + c], v);
        W2[idx] = __float2bfloat16(v);
    }
}

// -------- transpose (B,C,T) f32 -> (B,T,C) bf16, with mask -------------
__global__ __launch_bounds__(256) void transpose_in_kernel(
    const float* __restrict__ x, const float* __restrict__ mask,
    __hip_bfloat16* __restrict__ xw)
{
    __shared__ float tile[64][65];
    int b = blockIdx.z, c0 = blockIdx.y * 64, t0 = blockIdx.x * 64;
#pragma unroll
    for (int it = 0; it < 4; ++it) {
        int i = it * 256 + threadIdx.x;
        int r = i >> 4, cq = i & 15;
        float4 xv = *(const float4*)(&x[((size_t)b * C_ + c0 + r) * T_ + t0 + cq * 4]);
        float4 mv = *(const float4*)(&mask[(size_t)b * T_ + t0 + cq * 4]);
        tile[r][cq * 4 + 0] = xv.x * mv.x;
        tile[r][cq * 4 + 1] = xv.y * mv.y;
        tile[r][cq * 4 + 2] = xv.z * mv.z;
        tile[r][cq * 4 + 3] = xv.w * mv.w;
    }
    __syncthreads();
#pragma unroll
    for (int it = 0; it < 4; ++it) {
        int i = it * 256 + threadIdx.x;
        int r = i >> 4, cq = i & 15;
        union { __hip_bfloat16 h[4]; int2 i2; } u;
#pragma unroll
        for (int j = 0; j < 4; ++j) u.h[j] = __float2bfloat16(tile[cq * 4 + j][r]);
        *(int2*)(&xw[((size_t)b * T_ + t0 + r) * C_ + c0 + cq * 4]) = u.i2;
    }
}

// ======================= fused layer, cross-tile pipeline ==============
struct StageRegs { bf16x4 xv[4][3][3]; };   // [row][k3][quad], 72 VGPRs

static __device__ __forceinline__ void stage_load(
    const __hip_bfloat16* __restrict__ xin, size_t xbase,
    int t0s, int dil, int grp, int cbase, StageRegs& sr)
{
#pragma unroll
    for (int rr = 0; rr < 4; ++rr) {
        int t = t0s + grp * 4 + rr;
#pragma unroll
        for (int k3 = 0; k3 < 3; ++k3) {
            int tt = t - k3 * dil;
            bool ok = (tt >= 0);
            const __hip_bfloat16* rp =
                xin + xbase + (size_t)(ok ? tt : 0) * C_ + cbase;
#pragma unroll
            for (int q = 0; q < 3; ++q) {
                bf16x4 z = *(const bf16x4*)(rp + q * 4);
                if (!ok) z = (bf16x4){0, 0, 0, 0};
                sr.xv[rr][k3][q] = z;
            }
        }
    }
}

static __device__ __forceinline__ void stage_compute(
    const StageRegs& sr,
    const float* __restrict__ dw, const float* __restrict__ db,
    const float* __restrict__ gamma, const float* __restrict__ beta,
    const float* __restrict__ mask,
    int b, int t0s, int grp, int cbase,
    __hip_bfloat16 (* __restrict__ Hst)[HS_STRIDE])
{
    float4 wf[9], dbf[3], gaf[3], bef[3];
#pragma unroll
    for (int q = 0; q < 9; ++q) wf[q] = *(const float4*)(dw + cbase * 3 + q * 4);
#pragma unroll
    for (int q = 0; q < 3; ++q) {
        dbf[q] = *(const float4*)(db + cbase + q * 4);
        gaf[q] = *(const float4*)(gamma + cbase + q * 4);
        bef[q] = *(const float4*)(beta + cbase + q * 4);
    }
#pragma unroll
    for (int rr = 0; rr < 4; ++rr) {
        int tl = grp * 4 + rr;
        int t = t0s + tl;
        float v[12];
#pragma unroll
        for (int j = 0; j < 12; ++j) v[j] = ((const float*)dbf)[j];
#pragma unroll
        for (int k3 = 0; k3 < 3; ++k3)
#pragma unroll
            for (int q = 0; q < 3; ++q)
#pragma unroll
                for (int jj = 0; jj < 4; ++jj) {
                    int j = q * 4 + jj;
                    v[j] = fmaf(((const float*)wf)[j * 3 + k3],
                                bf2f(sr.xv[rr][k3][q][jj]), v[j]);
                }
        float s = 0.f, sq = 0.f;
#pragma unroll
        for (int j = 0; j < 12; ++j) { s += v[j]; sq = fmaf(v[j], v[j], sq); }
#pragma unroll
        for (int o = 1; o <= 8; o <<= 1) {
            s += __shfl_xor(s, o, 64);
            sq += __shfl_xor(sq, o, 64);
        }
        float mu = s * (1.f / C_);
        float var = fmaf(sq, 1.f / C_, -mu * mu);
        float rs = rsqrtf(var + 1e-5f);
        float m = mask[(size_t)b * T_ + t];
        union { __hip_bfloat16 h[12]; int2 i2[3]; } u;
#pragma unroll
        for (int j = 0; j < 12; ++j) {
            float xn = (v[j] - mu) * rs;
            u.h[j] = __float2bfloat16(
                fmaf(xn, ((const float*)gaf)[j], ((const float*)bef)[j]) * m);
        }
#pragma unroll
        for (int q = 0; q < 3; ++q)
            *(int2*)(&Hst[tl][cbase + q * 4]) = u.i2[q];
    }
}

template<int NT, bool LAST>
__global__ __launch_bounds__(256, 2) void ffn_fused_kernel(
    const __hip_bfloat16* __restrict__ xin, __hip_bfloat16* __restrict__ xout,
    const float* __restrict__ dw, const float* __restrict__ db,
    const float* __restrict__ gamma, const float* __restrict__ beta,
    const float* __restrict__ mask,
    const __hip_bfloat16* __restrict__ W1, const float* __restrict__ b1,
    const __hip_bfloat16* __restrict__ W2, const float* __restrict__ b2,
    int dil, float* __restrict__ outF)
{
    __shared__ __align__(16) char smem[76288];
    __hip_bfloat16 (*Hs)[HS_STRIDE]  = (__hip_bfloat16 (*)[HS_STRIDE])smem;     // 25856 B
    __hip_bfloat16 (*H1s)[H1S_STRIDE] =
        (__hip_bfloat16 (*)[H1S_STRIDE])(smem + 25856);                          // 50432 B

    const int bid = blockIdx.x;
    const int b = bid & 7;                       // batch pinned per XCD
    const int tbase = (bid >> 3) * 64 * NT;
    const int tid = threadIdx.x;
    const int wv = tid >> 6, lane = tid & 63;
    const int l31 = lane & 31, khalf = lane >> 5;   // 32x32 fragment coords
    const int grp = tid >> 4, cbase = (tid & 15) * 12;
    const size_t xbase = (size_t)b * T_ * C_;
    const __hip_bfloat16* W1b = W1 + (size_t)b * E_ * C_;
    const __hip_bfloat16* W2b = W2 + (size_t)b * C_ * E_;

    StageRegs sr;
    stage_load(xin, xbase, tbase, dil, grp, cbase, sr);
    stage_compute(sr, dw, db, gamma, beta, mask, b, tbase, grp, cbase, Hs);
    __syncthreads();

#pragma unroll
    for (int it = 0; it < NT; ++it) {
        const int t0 = tbase + it * 64;

        // issue next tile's x loads early: latency hides under GEMM1+GEMM2
        if (it + 1 < NT)
            stage_load(xin, xbase, t0 + 64, dil, grp, cbase, sr);

        // ---- GEMM1 (32x32x16): wave owns e-quarter [wv*96,+96), t 0..63 ----
        // 3 m-tiles x 2 n-tiles of 32x32; K=192 in 12 steps of 16.
        const __hip_bfloat16* w1p =
            W1b + (size_t)(wv * 96 + l31) * C_ + khalf * 8;
        f32x16 acc1[3][2] = {};
#pragma unroll
        for (int kk = 0; kk < 12; ++kk) {
            bf16x8 bfr[2];
#pragma unroll
            for (int nt2 = 0; nt2 < 2; ++nt2)
                bfr[nt2] = *(const bf16x8*)(&Hs[nt2 * 32 + l31][kk * 16 + khalf * 8]);
#pragma unroll
            for (int mt = 0; mt < 3; ++mt) {
                bf16x8 af = *(const bf16x8*)(w1p + (size_t)mt * 32 * C_ + kk * 16);
#pragma unroll
                for (int nt2 = 0; nt2 < 2; ++nt2)
                    acc1[mt][nt2] = __builtin_amdgcn_mfma_f32_32x32x16_bf16(
                        af, bfr[nt2], acc1[mt][nt2], 0, 0, 0);
            }
        }

        // ---- epilogue1: + b1, GELU -> H1s ----
        // C/D layout: col(t)=l31, row(e)=4*khalf + 8*(reg>>2) + (reg&3)
#pragma unroll
        for (int mt = 0; mt < 3; ++mt)
#pragma unroll
            for (int nt2 = 0; nt2 < 2; ++nt2) {
                int trow = nt2 * 32 + l31;
#pragma unroll
                for (int q = 0; q < 4; ++q) {
                    int e0 = wv * 96 + mt * 32 + khalf * 4 + q * 8;
                    float4 b1v = *(const float4*)(b1 + e0);
                    union { __hip_bfloat16 h[4]; int2 i2; } u;
#pragma unroll
                    for (int r = 0; r < 4; ++r)
                        u.h[r] = __float2bfloat16(gelu_fast(
                            acc1[mt][nt2][4 * q + r] + ((const float*)&b1v)[r]));
                    *(int2*)(&H1s[trow][e0]) = u.i2;
                }
            }
        __syncthreads();   // H1s ready; Hs(it) dead (all GEMM1 reads done)

        // ---- GEMM2 (32x32x16): wave (wm=c-half 96, wn=t-half 32) ----
        // 3 m-tiles of 32x32; K=384 in 24 steps of 16.
        const int wm = wv >> 1, wn = wv & 1;
        const __hip_bfloat16* w2p =
            W2b + (size_t)(wm * 96 + l31) * E_ + khalf * 8;
        f32x16 acc2[3] = {};
#pragma unroll
        for (int kk = 0; kk < 24; ++kk) {
            bf16x8 bfr = *(const bf16x8*)(&H1s[wn * 32 + l31][kk * 16 + khalf * 8]);
#pragma unroll
            for (int mt = 0; mt < 3; ++mt) {
                bf16x8 af = *(const bf16x8*)(w2p + (size_t)mt * 32 * E_ + kk * 16);
                acc2[mt] = __builtin_amdgcn_mfma_f32_32x32x16_bf16(
                    af, bfr, acc2[mt], 0, 0, 0);
            }
        }

        if (!LAST) {
            // ---- epilogue2: + b2 + residual, write xout (bf16) ----
            int t = t0 + wn * 32 + l31;
            const __hip_bfloat16* pr = xin + xbase + (size_t)t * C_;
            __hip_bfloat16* po = xout + xbase + (size_t)t * C_;
#pragma unroll
            for (int mt = 0; mt < 3; ++mt)
#pragma unroll
                for (int q = 0; q < 4; ++q) {
                    int c0 = wm * 96 + mt * 32 + khalf * 4 + q * 8;
                    float4 b2v = *(const float4*)(b2 + c0);
                    union { __hip_bfloat16 h[4]; int2 i2; } ui, uo;
                    ui.i2 = *(const int2*)(pr + c0);
#pragma unroll
                    for (int r = 0; r < 4; ++r)
                        uo.h[r] = __float2bfloat16(
                            bf2f(*(short*)&ui.h[r]) + acc2[mt][4 * q + r]
                            + ((const float*)&b2v)[r]);
                    *(int2*)(po + c0) = uo.i2;
                }
            // next tile's staging VALU overlaps with other waves' GEMM2/epi2
            if (it + 1 < NT) {
                stage_compute(sr, dw, db, gamma, beta, mask, b, t0 + 64, grp, cbase, Hs);
                __syncthreads();   // Hs(it+1) ready for next GEMM1
            }
        } else {
            // last layer: f32 result -> LDS tile [c][t] -> coalesced (B,C,T) out
            float (*Tile)[68] = (float (*)[68])smem;     // 52224 B, aliases Hs/H1s
            __syncthreads();   // everyone done reading H1s (Tile aliases it)
            {
                int tl = wn * 32 + l31;
                const __hip_bfloat16* pr = xin + xbase + (size_t)(t0 + tl) * C_;
#pragma unroll
                for (int mt = 0; mt < 3; ++mt)
#pragma unroll
                    for (int q = 0; q < 4; ++q) {
                        int c0 = wm * 96 + mt * 32 + khalf * 4 + q * 8;
                        float4 b2v = *(const float4*)(b2 + c0);
                        union { __hip_bfloat16 h[4]; int2 i2; } ui;
                        ui.i2 = *(const int2*)(pr + c0);
#pragma unroll
                        for (int r = 0; r < 4; ++r)
                            Tile[c0 + r][tl] =
                                bf2f(*(short*)&ui.h[r]) + acc2[mt][4 * q + r]
                                + ((const float*)&b2v)[r];
                    }
            }
            __syncthreads();
#pragma unroll
            for (int it2 = 0; it2 < 12; ++it2) {
                int i = it2 * 256 + tid;
                int r = i >> 4, tq = i & 15;
                float4 o = *(const float4*)(&Tile[r][tq * 4]);
                *(float4*)(&outF[((size_t)b * C_ + r) * T_ + t0 + tq * 4]) = o;
            }
        }
    }
}

extern "C" void kernel_launch(void* const* d_in, const int* in_sizes, int n_in,
                              void* d_out, int out_size, void* d_ws, size_t ws_size,
                              hipStream_t stream) {
    const float* x        = (const float*)d_in[0];
    const float* x_mask   = (const float*)d_in[1];
    const float* g        = (const float*)d_in[2];
    const float* dconv_w  = (const float*)d_in[3];
    const float* dconv_b  = (const float*)d_in[4];
    const float* ln_gamma = (const float*)d_in[5];
    const float* ln_beta  = (const float*)d_in[6];
    const float* p1_w     = (const float*)d_in[7];
    const float* p1_b     = (const float*)d_in[8];
    const float* p1_ain_w = (const float*)d_in[9];
    const float* p1_ain_b = (const float*)d_in[10];
    const float* p1_aout_w= (const float*)d_in[11];
    const float* p1_aout_b= (const float*)d_in[12];
    const float* p2_w     = (const float*)d_in[13];
    const float* p2_b     = (const float*)d_in[14];
    const float* p2_ain_w = (const float*)d_in[15];
    const float* p2_ain_b = (const float*)d_in[16];
    const float* p2_aout_w= (const float*)d_in[17];
    const float* p2_aout_b= (const float*)d_in[18];

    char* ws = (char*)d_ws;
    size_t off = 0;
    __hip_bfloat16* xwA = (__hip_bfloat16*)(ws + off); off += (size_t)B_ * T_ * C_ * 2;
    __hip_bfloat16* xwB = (__hip_bfloat16*)(ws + off); off += (size_t)B_ * T_ * C_ * 2;
    __hip_bfloat16* W1 = (__hip_bfloat16*)(ws + off);  off += (size_t)L_ * B_ * E_ * C_ * 2;
    __hip_bfloat16* W2 = (__hip_bfloat16*)(ws + off);  off += (size_t)L_ * B_ * C_ * E_ * 2;
    float* A1in  = (float*)(ws + off); off += (size_t)L_ * B_ * C_ * R_ * 4;
    float* A1out = (float*)(ws + off); off += (size_t)L_ * B_ * R_ * E_ * 4;
    float* A2in  = (float*)(ws + off); off += (size_t)L_ * B_ * E_ * R_ * 4;
    float* A2out = (float*)(ws + off); off += (size_t)L_ * B_ * R_ * C_ * 4;

    {
        int total = L_ * B_ * (2 * C_ * R_ + 2 * E_ * R_);
        adapters_kernel<<<(total + 255) / 256, 256, 0, stream>>>(
            g,
            p1_ain_w, p1_ain_b, A1in,
            p1_aout_w, p1_aout_b, A1out,
            p2_ain_w, p2_ain_b, A2in,
            p2_aout_w, p2_aout_b, A2out);
    }
    {
        int w1blocks = (L_ * B_ * E_ * C_) / 256;
        builds_kernel<<<2 * w1blocks, 256, 0, stream>>>(
            p1_w, p2_w, A1in, A1out, A2in, A2out, W1, W2);
    }

    transpose_in_kernel<<<dim3(T_ / 64, C_ / 64, B_), 256, 0, stream>>>(x, x_mask, xwA);

    const int DILS[3] = {1, 3, 9};
    __hip_bfloat16* bufs[2] = {xwA, xwB};
    for (int l = 0; l < L_; ++l) {
        if (l < L_ - 1) {
            // NT=2: grid 512 (all blocks co-resident at 2/CU, zero tail)
            ffn_fused_kernel<2, false><<<(T_ / 128) * B_, 256, 0, stream>>>(
                bufs[l & 1], bufs[(l & 1) ^ 1],
                dconv_w + l * C_ * K_, dconv_b + l * C_,
                ln_gamma + l * C_, ln_beta + l * C_, x_mask,
                W1 + (size_t)l * B_ * E_ * C_, p1_b + l * E_,
                W2 + (size_t)l * B_ * C_ * E_, p2_b + l * C_, DILS[l], nullptr);
        } else {
            // last layer: fused (B,C,T) f32 output, NT=1
            ffn_fused_kernel<1, true><<<(T_ / 64) * B_, 256, 0, stream>>>(
                bufs[l & 1], bufs[(l & 1) ^ 1],
                dconv_w + l * C_ * K_, dconv_b + l * C_,
                ln_gamma + l * C_, ln_beta + l * C_, x_mask,
                W1 + (size_t)l * B_ * E_ * C_, p1_b + l * E_,
                W2 + (size_t)l * B_ * C_ * E_, p2_b + l * C_, DILS[l], (float*)d_out);
        }
    }
}

// Round 22
// 227.599 us; speedup vs baseline: 1.2376x; 1.2376x over previous
//
#include <hip/hip_runtime.h>
#include <hip/hip_bf16.h>

#define B_ 8
#define C_ 192
#define G_ 256
#define E_ 384
#define R_ 4
#define T_ 8192
#define L_ 3
#define K_ 3

typedef __attribute__((ext_vector_type(4))) float f32x4;
typedef __attribute__((ext_vector_type(8))) short bf16x8;
typedef __attribute__((ext_vector_type(4))) short bf16x4;

static __device__ __forceinline__ float bf2f(short u) {
    union { float f; unsigned int i; } z;
    z.i = ((unsigned int)(unsigned short)u) << 16;
    return z.f;
}

// tanh-form GELU: max abs err vs erf-form ~1e-3 (absmax 0.078 measured).
static __device__ __forceinline__ float gelu_fast(float x) {
    float x2 = x * x;
    float inner = fmaf(0.044715f * x, x2, x);
    float e = __expf(1.5957691216057308f * inner);   // e^{2z}
    float r = 1.0f / (e + 1.0f);
    float t = fmaf(-2.0f, r, 1.0f);                  // tanh(z)
    float s = 0.5f * x;
    return fmaf(s, t, s);
}

// ---------- all 4 adapter projections in one launch --------------------
__global__ __launch_bounds__(256) void adapters_kernel(
    const float* __restrict__ g2,
    const float* __restrict__ w0, const float* __restrict__ bi0, float* __restrict__ o0,
    const float* __restrict__ w1, const float* __restrict__ bi1, float* __restrict__ o1,
    const float* __restrict__ w2, const float* __restrict__ bi2, float* __restrict__ o2,
    const float* __restrict__ w3, const float* __restrict__ bi3, float* __restrict__ o3)
{
    const int N0 = L_ * B_ * (C_ * R_);     // 18432
    const int N1 = L_ * B_ * (E_ * R_);     // 36864
    int idx = blockIdx.x * 256 + threadIdx.x;
    const float* w; const float* bi; float* o; int rows; int li;
    if (idx < N0)                      { w=w0; bi=bi0; o=o0; rows=C_*R_; li=idx; }
    else if ((idx -= N0) < N1)         { w=w1; bi=bi1; o=o1; rows=E_*R_; li=idx; }
    else if ((idx -= N1) < N1)         { w=w2; bi=bi2; o=o2; rows=E_*R_; li=idx; }
    else if ((idx -= N1) < N0)         { w=w3; bi=bi3; o=o3; rows=C_*R_; li=idx; }
    else return;
    int bb = li & 7;
    int lr = li >> 3;
    const float4* wr = (const float4*)(w + (size_t)lr * G_);
    const float4* gb = (const float4*)(g2 + (size_t)bb * G_);
    float s = bi[lr];
#pragma unroll 8
    for (int g = 0; g < G_ / 4; ++g) {
        float4 a = gb[g], b = wr[g];
        s = fmaf(a.x, b.x, s); s = fmaf(a.y, b.y, s);
        s = fmaf(a.z, b.z, s); s = fmaf(a.w, b.w, s);
    }
    o[((size_t)(lr / rows) * B_ + bb) * rows + (lr % rows)] = s;
}

// ---------- W1eff, W2eff (plain; LN affine applied in staging) ---------
__global__ __launch_bounds__(256) void builds_kernel(
    const float* __restrict__ p1w, const float* __restrict__ p2w,
    const float* __restrict__ A1in, const float* __restrict__ A1out,
    const float* __restrict__ A2in, const float* __restrict__ A2out,
    __hip_bfloat16* __restrict__ W1, __hip_bfloat16* __restrict__ W2)
{
    const int W1B = (L_ * B_ * E_ * C_) / 256;   // 6912 blocks
    int blk = blockIdx.x;
    if (blk < W1B) {
        int idx = blk * 256 + threadIdx.x;
        int c = idx % C_;
        int e = (idx / C_) % E_;
        int b = (idx / (C_ * E_)) % B_;
        int l = idx / (C_ * E_ * B_);
        float v = p1w[((size_t)l * E_ + e) * C_ + c];
        const float* ai = A1in + ((size_t)l * B_ + b) * (C_ * R_);
        const float* ao = A1out + ((size_t)l * B_ + b) * (R_ * E_);
#pragma unroll
        for (int r = 0; r < R_; ++r) v = fmaf(ai[c * R_ + r], ao[r * E_ + e], v);
        W1[idx] = __float2bfloat16(v);
    } else {
        int idx = (blk - W1B) * 256 + threadIdx.x;
        int e = idx % E_;
        int c = (idx / E_) % C_;
        int b = (idx / (C_ * E_)) % B_;
        int l = idx / (C_ * E_ * B_);
        float v = p2w[((size_t)l * C_ + c) * E_ + e];
        const float* ai = A2in + ((size_t)l * B_ + b) * (E_ * R_);
        const float* ao = A2out + ((size_t)l * B_ + b) * (R_ * C_);
#pragma unroll
        for (int r = 0; r < R_; ++r) v = fmaf(ai[e * R_ + r], ao[r * C_ + c], v);
        W2[idx] = __float2bfloat16(v);
    }
}

// -------- transpose (B,C,T) f32 -> (B,T,C) bf16, with mask -------------
__global__ __launch_bounds__(256) void transpose_in_kernel(
    const float* __restrict__ x, const float* __restrict__ mask,
    __hip_bfloat16* __restrict__ xw)
{
    __shared__ float tile[64][65];
    int b = blockIdx.z, c0 = blockIdx.y * 64, t0 = blockIdx.x * 64;
#pragma unroll
    for (int it = 0; it < 4; ++it) {
        int i = it * 256 + threadIdx.x;
        int r = i >> 4, cq = i & 15;
        float4 xv = *(const float4*)(&x[((size_t)b * C_ + c0 + r) * T_ + t0 + cq * 4]);
        float4 mv = *(const float4*)(&mask[(size_t)b * T_ + t0 + cq * 4]);
        tile[r][cq * 4 + 0] = xv.x * mv.x;
        tile[r][cq * 4 + 1] = xv.y * mv.y;
        tile[r][cq * 4 + 2] = xv.z * mv.z;
        tile[r][cq * 4 + 3] = xv.w * mv.w;
    }
    __syncthreads();
#pragma unroll
    for (int it = 0; it < 4; ++it) {
        int i = it * 256 + threadIdx.x;
        int r = i >> 4, cq = i & 15;
        union { __hip_bfloat16 h[4]; int2 i2; } u;
#pragma unroll
        for (int j = 0; j < 4; ++j) u.h[j] = __float2bfloat16(tile[cq * 4 + j][r]);
        *(int2*)(&xw[((size_t)b * T_ + t0 + r) * C_ + c0 + cq * 4]) = u.i2;
    }
}

// ======================= fused layer, cross-tile pipeline ==============
struct StageRegs { bf16x4 xv[4][3][3]; };   // [row][k3][quad], 72 VGPRs

static __device__ __forceinline__ void stage_load(
    const __hip_bfloat16* __restrict__ xin, size_t xbase,
    int t0s, int dil, int grp, int cbase, StageRegs& sr)
{
#pragma unroll
    for (int rr = 0; rr < 4; ++rr) {
        int t = t0s + grp * 4 + rr;
#pragma unroll
        for (int k3 = 0; k3 < 3; ++k3) {
            int tt = t - k3 * dil;
            bool ok = (tt >= 0);
            const __hip_bfloat16* rp =
                xin + xbase + (size_t)(ok ? tt : 0) * C_ + cbase;
#pragma unroll
            for (int q = 0; q < 3; ++q) {
                bf16x4 z = *(const bf16x4*)(rp + q * 4);
                if (!ok) z = (bf16x4){0, 0, 0, 0};
                sr.xv[rr][k3][q] = z;
            }
        }
    }
}

static __device__ __forceinline__ void stage_compute(
    const StageRegs& sr,
    const float* __restrict__ dw, const float* __restrict__ db,
    const float* __restrict__ gamma, const float* __restrict__ beta,
    const float* __restrict__ mask,
    int b, int t0s, int grp, int cbase,
    __hip_bfloat16 (* __restrict__ Hst)[C_ + 8])
{
    float4 wf[9], dbf[3], gaf[3], bef[3];
#pragma unroll
    for (int q = 0; q < 9; ++q) wf[q] = *(const float4*)(dw + cbase * 3 + q * 4);
#pragma unroll
    for (int q = 0; q < 3; ++q) {
        dbf[q] = *(const float4*)(db + cbase + q * 4);
        gaf[q] = *(const float4*)(gamma + cbase + q * 4);
        bef[q] = *(const float4*)(beta + cbase + q * 4);
    }
#pragma unroll
    for (int rr = 0; rr < 4; ++rr) {
        int tl = grp * 4 + rr;
        int t = t0s + tl;
        float v[12];
#pragma unroll
        for (int j = 0; j < 12; ++j) v[j] = ((const float*)dbf)[j];
#pragma unroll
        for (int k3 = 0; k3 < 3; ++k3)
#pragma unroll
            for (int q = 0; q < 3; ++q)
#pragma unroll
                for (int jj = 0; jj < 4; ++jj) {
                    int j = q * 4 + jj;
                    v[j] = fmaf(((const float*)wf)[j * 3 + k3],
                                bf2f(sr.xv[rr][k3][q][jj]), v[j]);
                }
        float s = 0.f, sq = 0.f;
#pragma unroll
        for (int j = 0; j < 12; ++j) { s += v[j]; sq = fmaf(v[j], v[j], sq); }
#pragma unroll
        for (int o = 1; o <= 8; o <<= 1) {
            s += __shfl_xor(s, o, 64);
            sq += __shfl_xor(sq, o, 64);
        }
        float mu = s * (1.f / C_);
        float var = fmaf(sq, 1.f / C_, -mu * mu);
        float rs = rsqrtf(var + 1e-5f);
        float m = mask[(size_t)b * T_ + t];
        union { __hip_bfloat16 h[12]; int2 i2[3]; } u;
#pragma unroll
        for (int j = 0; j < 12; ++j) {
            float xn = (v[j] - mu) * rs;
            u.h[j] = __float2bfloat16(
                fmaf(xn, ((const float*)gaf)[j], ((const float*)bef)[j]) * m);
        }
#pragma unroll
        for (int q = 0; q < 3; ++q)
            *(int2*)(&Hst[tl][cbase + q * 4]) = u.i2[q];
    }
}

template<int NT, bool LAST>
__global__ __launch_bounds__(256, 2) void ffn_fused_kernel(
    const __hip_bfloat16* __restrict__ xin, __hip_bfloat16* __restrict__ xout,
    const float* __restrict__ dw, const float* __restrict__ db,
    const float* __restrict__ gamma, const float* __restrict__ beta,
    const float* __restrict__ mask,
    const __hip_bfloat16* __restrict__ W1, const float* __restrict__ b1,
    const __hip_bfloat16* __restrict__ W2, const float* __restrict__ b2,
    int dil, float* __restrict__ outF)
{
    __shared__ __align__(16) char smem[75776];
    __hip_bfloat16 (*Hs)[C_ + 8]  = (__hip_bfloat16 (*)[C_ + 8])smem;           // 25600 B
    __hip_bfloat16 (*H1s)[E_ + 8] = (__hip_bfloat16 (*)[E_ + 8])(smem + 25600); // 50176 B

    const int bid = blockIdx.x;
    const int b = bid & 7;                       // batch pinned per XCD
    const int tbase = (bid >> 3) * 64 * NT;
    const int tid = threadIdx.x;
    const int wv = tid >> 6, lane = tid & 63;
    const int llo = lane & 15, lhi = lane >> 4;
    const int grp = tid >> 4, cbase = (tid & 15) * 12;
    const size_t xbase = (size_t)b * T_ * C_;
    const __hip_bfloat16* W1b = W1 + (size_t)b * E_ * C_;
    const __hip_bfloat16* W2b = W2 + (size_t)b * C_ * E_;

    StageRegs sr;
    stage_load(xin, xbase, tbase, dil, grp, cbase, sr);
    stage_compute(sr, dw, db, gamma, beta, mask, b, tbase, grp, cbase, Hs);
    __syncthreads();

#pragma unroll
    for (int it = 0; it < NT; ++it) {
        const int t0 = tbase + it * 64;

        // issue next tile's x loads early: latency hides under GEMM1+GEMM2
        if (it + 1 < NT)
            stage_load(xin, xbase, t0 + 64, dil, grp, cbase, sr);

        // ---- GEMM1: wave owns e-quarter [wv*96, +96), all 64 t ----
        const __hip_bfloat16* w1p = W1b + (size_t)(wv * 96 + llo) * C_ + lhi * 8;
        f32x4 acc1[6][4] = {};
#pragma unroll
        for (int kc = 0; kc < 6; ++kc) {
            bf16x8 bfr[4];
#pragma unroll
            for (int nf = 0; nf < 4; ++nf)
                bfr[nf] = *(const bf16x8*)(&Hs[nf * 16 + llo][kc * 32 + lhi * 8]);
#pragma unroll
            for (int mf = 0; mf < 6; ++mf) {
                bf16x8 af = *(const bf16x8*)(w1p + (size_t)mf * 16 * C_ + kc * 32);
#pragma unroll
                for (int nf = 0; nf < 4; ++nf)
                    acc1[mf][nf] = __builtin_amdgcn_mfma_f32_16x16x32_bf16(
                        af, bfr[nf], acc1[mf][nf], 0, 0, 0);
            }
        }

        // ---- epilogue1: + b1, GELU -> H1s ----
#pragma unroll
        for (int mf = 0; mf < 6; ++mf) {
            int e0 = wv * 96 + mf * 16 + lhi * 4;
            float4 b1v = *(const float4*)(b1 + e0);
#pragma unroll
            for (int nf = 0; nf < 4; ++nf) {
                union { __hip_bfloat16 h[4]; int2 i2; } u;
#pragma unroll
                for (int j = 0; j < 4; ++j) {
                    float xx = acc1[mf][nf][j] + ((const float*)&b1v)[j];
                    u.h[j] = __float2bfloat16(gelu_fast(xx));
                }
                *(int2*)(&H1s[nf * 16 + llo][e0]) = u.i2;
            }
        }
        __syncthreads();   // H1s ready; Hs(it) dead (all GEMM1 reads done)

        // ---- GEMM2: wave owns c-quarter [wv*48, +48), all 64 t ----
        const __hip_bfloat16* w2p = W2b + (size_t)(wv * 48 + llo) * E_ + lhi * 8;
        f32x4 acc2[3][4] = {};
#pragma unroll
        for (int kc = 0; kc < 12; ++kc) {
            bf16x8 bfr[4];
#pragma unroll
            for (int nf = 0; nf < 4; ++nf)
                bfr[nf] = *(const bf16x8*)(&H1s[nf * 16 + llo][kc * 32 + lhi * 8]);
#pragma unroll
            for (int mf = 0; mf < 3; ++mf) {
                bf16x8 af = *(const bf16x8*)(w2p + (size_t)mf * 16 * E_ + kc * 32);
#pragma unroll
                for (int nf = 0; nf < 4; ++nf)
                    acc2[mf][nf] = __builtin_amdgcn_mfma_f32_16x16x32_bf16(
                        af, bfr[nf], acc2[mf][nf], 0, 0, 0);
            }
        }

        if (!LAST) {
            // ---- epilogue2: + b2 + residual, write xout (bf16) ----
#pragma unroll
            for (int mf = 0; mf < 3; ++mf) {
                int c0 = wv * 48 + mf * 16 + lhi * 4;
                float4 b2v = *(const float4*)(b2 + c0);
#pragma unroll
                for (int nf = 0; nf < 4; ++nf) {
                    int t = t0 + nf * 16 + llo;
                    const __hip_bfloat16* pr = xin + xbase + (size_t)t * C_ + c0;
                    __hip_bfloat16* po = xout + xbase + (size_t)t * C_ + c0;
                    union { __hip_bfloat16 h[4]; int2 i2; } ui, uo;
                    ui.i2 = *(const int2*)pr;
#pragma unroll
                    for (int j = 0; j < 4; ++j)
                        uo.h[j] = __float2bfloat16(
                            bf2f(*(short*)&ui.h[j]) + acc2[mf][nf][j] + ((const float*)&b2v)[j]);
                    *(int2*)po = uo.i2;
                }
            }
            // next tile's staging VALU overlaps with other waves' GEMM2/epi2
            if (it + 1 < NT) {
                stage_compute(sr, dw, db, gamma, beta, mask, b, t0 + 64, grp, cbase, Hs);
                __syncthreads();   // Hs(it+1) ready for next GEMM1
            }
        } else {
            // last layer: f32 result -> LDS tile [c][t] -> coalesced (B,C,T) out
            float (*Tile)[68] = (float (*)[68])smem;     // 52224 B, aliases Hs/H1s
            __syncthreads();   // everyone done reading H1s (Tile aliases it)
#pragma unroll
            for (int mf = 0; mf < 3; ++mf) {
                int c0 = wv * 48 + mf * 16 + lhi * 4;
                float4 b2v = *(const float4*)(b2 + c0);
#pragma unroll
                for (int nf = 0; nf < 4; ++nf) {
                    int tl = nf * 16 + llo;
                    const __hip_bfloat16* pr = xin + xbase + (size_t)(t0 + tl) * C_ + c0;
                    union { __hip_bfloat16 h[4]; int2 i2; } ui;
                    ui.i2 = *(const int2*)pr;
#pragma unroll
                    for (int j = 0; j < 4; ++j)
                        Tile[c0 + j][tl] =
                            bf2f(*(short*)&ui.h[j]) + acc2[mf][nf][j] + ((const float*)&b2v)[j];
                }
            }
            __syncthreads();
#pragma unroll
            for (int it2 = 0; it2 < 12; ++it2) {
                int i = it2 * 256 + tid;
                int r = i >> 4, tq = i & 15;
                float4 o = *(const float4*)(&Tile[r][tq * 4]);
                *(float4*)(&outF[((size_t)b * C_ + r) * T_ + t0 + tq * 4]) = o;
            }
        }
    }
}

extern "C" void kernel_launch(void* const* d_in, const int* in_sizes, int n_in,
                              void* d_out, int out_size, void* d_ws, size_t ws_size,
                              hipStream_t stream) {
    const float* x        = (const float*)d_in[0];
    const float* x_mask   = (const float*)d_in[1];
    const float* g        = (const float*)d_in[2];
    const float* dconv_w  = (const float*)d_in[3];
    const float* dconv_b  = (const float*)d_in[4];
    const float* ln_gamma = (const float*)d_in[5];
    const float* ln_beta  = (const float*)d_in[6];
    const float* p1_w     = (const float*)d_in[7];
    const float* p1_b     = (const float*)d_in[8];
    const float* p1_ain_w = (const float*)d_in[9];
    const float* p1_ain_b = (const float*)d_in[10];
    const float* p1_aout_w= (const float*)d_in[11];
    const float* p1_aout_b= (const float*)d_in[12];
    const float* p2_w     = (const float*)d_in[13];
    const float* p2_b     = (const float*)d_in[14];
    const float* p2_ain_w = (const float*)d_in[15];
    const float* p2_ain_b = (const float*)d_in[16];
    const float* p2_aout_w= (const float*)d_in[17];
    const float* p2_aout_b= (const float*)d_in[18];

    char* ws = (char*)d_ws;
    size_t off = 0;
    __hip_bfloat16* xwA = (__hip_bfloat16*)(ws + off); off += (size_t)B_ * T_ * C_ * 2;
    __hip_bfloat16* xwB = (__hip_bfloat16*)(ws + off); off += (size_t)B_ * T_ * C_ * 2;
    __hip_bfloat16* W1 = (__hip_bfloat16*)(ws + off);  off += (size_t)L_ * B_ * E_ * C_ * 2;
    __hip_bfloat16* W2 = (__hip_bfloat16*)(ws + off);  off += (size_t)L_ * B_ * C_ * E_ * 2;
    float* A1in  = (float*)(ws + off); off += (size_t)L_ * B_ * C_ * R_ * 4;
    float* A1out = (float*)(ws + off); off += (size_t)L_ * B_ * R_ * E_ * 4;
    float* A2in  = (float*)(ws + off); off += (size_t)L_ * B_ * E_ * R_ * 4;
    float* A2out = (float*)(ws + off); off += (size_t)L_ * B_ * R_ * C_ * 4;

    {
        int total = L_ * B_ * (2 * C_ * R_ + 2 * E_ * R_);
        adapters_kernel<<<(total + 255) / 256, 256, 0, stream>>>(
            g,
            p1_ain_w, p1_ain_b, A1in,
            p1_aout_w, p1_aout_b, A1out,
            p2_ain_w, p2_ain_b, A2in,
            p2_aout_w, p2_aout_b, A2out);
    }
    {
        int w1blocks = (L_ * B_ * E_ * C_) / 256;
        builds_kernel<<<2 * w1blocks, 256, 0, stream>>>(
            p1_w, p2_w, A1in, A1out, A2in, A2out, W1, W2);
    }

    transpose_in_kernel<<<dim3(T_ / 64, C_ / 64, B_), 256, 0, stream>>>(x, x_mask, xwA);

    const int DILS[3] = {1, 3, 9};
    __hip_bfloat16* bufs[2] = {xwA, xwB};
    for (int l = 0; l < L_; ++l) {
        if (l < L_ - 1) {
            // NT=2: grid 512 (all blocks co-resident at 2/CU, zero tail)
            ffn_fused_kernel<2, false><<<(T_ / 128) * B_, 256, 0, stream>>>(
                bufs[l & 1], bufs[(l & 1) ^ 1],
                dconv_w + l * C_ * K_, dconv_b + l * C_,
                ln_gamma + l * C_, ln_beta + l * C_, x_mask,
                W1 + (size_t)l * B_ * E_ * C_, p1_b + l * E_,
                W2 + (size_t)l * B_ * C_ * E_, p2_b + l * C_, DILS[l], nullptr);
        } else {
            // last layer: fused (B,C,T) f32 output, NT=1
            ffn_fused_kernel<1, true><<<(T_ / 64) * B_, 256, 0, stream>>>(
                bufs[l & 1], bufs[(l & 1) ^ 1],
                dconv_w + l * C_ * K_, dconv_b + l * C_,
                ln_gamma + l * C_, ln_beta + l * C_, x_mask,
                W1 + (size_t)l * B_ * E_ * C_, p1_b + l * E_,
                W2 + (size_t)l * B_ * C_ * E_, p2_b + l * C_, DILS[l], (float*)d_out);
        }
    }
}